// Round 5
// baseline (107.787 us; speedup 1.0000x reference)
//
#include <hip/hip_runtime.h>

// DepthDeformConv — round 13: explicit register-pipelined tap loop.
//   r12 post-mortem: 1024-thr block capped VGPR at 128, compiler retreated
//   to 56 -> all prefetch/ILP destroyed, main 43->50us despite 4 waves/SIMD.
//   Registers-in-flight, not waves, hide this kernel's latency (r10 +5.3us
//   said the same). Fix: back to 512-thr / 8-wave / 128KB window (cap 256),
//   and hand-pipeline the 18 (tap,ks) stages: stage s+1's 4 LDS corner
//   reads + 4 L2 weight loads issue into the alternate named buffer while
//   stage s unpacks/blends/MFMAs. All buffers indexed by compile-time s&1
//   (fully unrolled -> no scratch). Stencil state double-buffered per tap.
//   Barrier-free taps, 27-scalar prefetch, XCD swizzle kept from r11.

typedef __attribute__((ext_vector_type(8))) short bf16x8;
typedef __attribute__((ext_vector_type(4))) float f32x4;
typedef __attribute__((ext_vector_type(4))) unsigned int u32x4;

#define HH 128
#define WW 128
#define CC 64
#define OO 64
#define HW (128 * 128)

__device__ __forceinline__ unsigned f32_to_bf16_rne(float f) {
    unsigned u = __float_as_uint(f);
    return (u + 0x7FFFu + ((u >> 16) & 1u)) >> 16;
}

// ---------------- kernel 1: fused NCHW->NHWC bf16 + weight repack ----------------
__global__ __launch_bounds__(256)
void prep_fused13(const float* __restrict__ input,
                  unsigned short* __restrict__ nhwc,
                  const float* __restrict__ weight,
                  unsigned short* __restrict__ wT2)
{
    __shared__ unsigned tile[64][33];
    const int tid = threadIdx.x;
    const int blk = blockIdx.x;

    if (blk >= 2048) {
        // weight repack: wT2[(kt*8 + c8)*64 + o] = bf16 w for ch c8*8..+7, tap kt
        const int d  = (blk - 2048) * 256 + tid;    // 0..4607
        const int o  = d & 63;
        const int k8 = d >> 6;                      // 0..71
        const int kt = k8 >> 3;
        const int c8 = k8 & 7;
        u32x4 pk;
        #pragma unroll
        for (int jj = 0; jj < 4; ++jj) {
            unsigned lo = f32_to_bf16_rne(weight[o * 576 + (c8 * 8 + 2 * jj)     * 9 + kt]);
            unsigned hi = f32_to_bf16_rne(weight[o * 576 + (c8 * 8 + 2 * jj + 1) * 9 + kt]);
            pk[jj] = lo | (hi << 16);
        }
        *(u32x4*)(wT2 + (size_t)d * 8) = pk;
        return;
    }

    const int b  = blk >> 9;
    const int y  = (blk >> 2) & 127;
    const int xbase = (blk & 3) * 32;
    #pragma unroll
    for (int it = 0; it < 8; ++it) {
        int flat = it * 256 + tid;          // 0..2047
        int c = flat >> 5, x = flat & 31;
        float v = input[((b * 64 + c) * 128 + y) * 128 + xbase + x];
        tile[c][x] = f32_to_bf16_rne(v);
    }
    __syncthreads();
    {
        int x = tid >> 3, cg = tid & 7;     // 32x * 8 channel-groups
        unsigned r0 = tile[cg * 8 + 0][x], r1 = tile[cg * 8 + 1][x];
        unsigned r2 = tile[cg * 8 + 2][x], r3 = tile[cg * 8 + 3][x];
        unsigned r4 = tile[cg * 8 + 4][x], r5 = tile[cg * 8 + 5][x];
        unsigned r6 = tile[cg * 8 + 6][x], r7 = tile[cg * 8 + 7][x];
        u32x4 pk;
        pk[0] = r0 | (r1 << 16); pk[1] = r2 | (r3 << 16);
        pk[2] = r4 | (r5 << 16); pk[3] = r6 | (r7 << 16);
        *(u32x4*)(nhwc + ((size_t)((b * 128 + y) * 128 + xbase + x)) * 64 + cg * 8) = pk;
    }
}

// ---------------- kernel 2: fused sample + MFMA, register-pipelined ----------------
__global__ __launch_bounds__(512, 2)
void ddc_pipe13(const unsigned short* __restrict__ nhwc,
                const unsigned short* __restrict__ wT2,
                const float* __restrict__ offset,
                const float* __restrict__ mask,
                const float* __restrict__ bias,
                float* __restrict__ out)
{
    // 8-row bf16 NHWC window, chunk-swizzled: LDS u32x4 index
    //   idx(slot,x,c8pos) = slot*1024 + x*8 + c8pos, holding source chunk
    //   c8pos ^ (x&7). Reader at chunk ch uses pos = ch ^ (x&7).
    __shared__ u32x4 win[8192];            // 128 KB (only LDS in kernel)

    const int blk0 = blockIdx.x;           // 512 = 4b * 128h
    const int blk  = (blk0 & 7) * 64 + (blk0 >> 3);   // XCD-chunked swizzle
    const int b    = blk >> 7;
    const int h    = blk & 127;
    const int tid  = threadIdx.x;
    const int wave = tid >> 6;             // 8 pixel groups
    const int lane = tid & 63;
    const int l15  = lane & 15;            // pixel within group / o-row (A)
    const int kq   = lane >> 4;            // k-chunk quad (0..3)
    const int wpix = wave * 16 + l15;      // w coordinate (full 128 row)

    f32x4 acc[4];
    #pragma unroll
    for (int mt = 0; mt < 4; ++mt) acc[mt] = (f32x4){0.f, 0.f, 0.f, 0.f};

    const unsigned short* nb = nhwc + (size_t)b * HW * CC;
    const u32x4* wsrc = (const u32x4*)wT2;

    // ---- prefetch all per-pixel stencil scalars (27 coalesced loads) ----
    float oyv[9], oxv[9], mv[9];
    #pragma unroll
    for (int kt = 0; kt < 9; ++kt) {
        oyv[kt] = offset[((b * 18 + 2 * kt)     * 128 + h) * 128 + wpix];
        oxv[kt] = offset[((b * 18 + 2 * kt + 1) * 128 + h) * 128 + wpix];
        mv[kt]  = mask  [((b * 9  + kt)         * 128 + h) * 128 + wpix];
    }

    // ---- stage window rows h-3..h+4 (swizzled source, linear LDS dest) ----
    #pragma unroll
    for (int i = 0; i < 16; ++i) {
        const int slot = i >> 1;                      // uniform per i
        const int y = h - 3 + slot;
        if (y >= 0 && y < HH) {
            const int q  = ((i & 1) << 9) + tid;      // 0..1023 within row
            const int x  = q >> 3;
            const int c8 = q & 7;
            win[slot * 1024 + q] =
                *(const u32x4*)(nb + ((size_t)(y * WW + x)) * CC + ((c8 ^ (x & 7)) << 3));
        }
    }
    __syncthreads();                                  // the ONLY barrier

    // ---- per-tap stencil state, double-buffered (slot = kt&1) ----
    int   r0a[2], r1a[2], bx0a[2], bx1a[2], sx0a[2], sx1a[2];
    int   gy0a[2], gy1a[2], gx0a[2], gx1a[2];
    bool  in0a[2], in1a[2];
    float c00a[2], c01a[2], c10a[2], c11a[2];

    auto stencil = [&](int kt, int sl) {
        const float oy = oyv[kt], ox = oxv[kt], m = mv[kt];
        const float py = (float)(h - 1 + kt / 3) + oy;
        const float px = (float)(wpix - 1 + kt % 3) + ox;
        const float y0f = floorf(py), x0f = floorf(px);
        const int y0 = (int)y0f, x0 = (int)x0f;
        const float wy = py - y0f, wx = px - x0f;
        const int y1 = y0 + 1, x1 = x0 + 1;
        const bool vy0 = (y0 >= 0) & (y0 < HH);
        const bool vy1 = (y1 >= 0) & (y1 < HH);
        const bool vx0 = (x0 >= 0) & (x0 < WW);
        const bool vx1 = (x1 >= 0) & (x1 < WW);
        const int y0c = min(max(y0, 0), HH - 1), y1c = min(max(y1, 0), HH - 1);
        const int x0c = min(max(x0, 0), WW - 1), x1c = min(max(x1, 0), WW - 1);
        const float wy1 = 1.f - wy, wx1 = 1.f - wx;
        c00a[sl] = (vy0 && vx0) ? wy1 * wx1 * m : 0.f;
        c01a[sl] = (vy0 && vx1) ? wy1 * wx  * m : 0.f;
        c10a[sl] = (vy1 && vx0) ? wy  * wx1 * m : 0.f;
        c11a[sl] = (vy1 && vx1) ? wy  * wx  * m : 0.f;
        const int s0 = y0c - (h - 3), s1 = y1c - (h - 3);
        in0a[sl] = ((unsigned)s0 < 8u);
        in1a[sl] = ((unsigned)s1 < 8u);
        r0a[sl] = (in0a[sl] ? s0 : 0) * 1024;
        r1a[sl] = (in1a[sl] ? s1 : 0) * 1024;
        bx0a[sl] = x0c * 8; sx0a[sl] = x0c & 7;
        bx1a[sl] = x1c * 8; sx1a[sl] = x1c & 7;
        gy0a[sl] = y0c; gy1a[sl] = y1c; gx0a[sl] = x0c; gx1a[sl] = x1c;
    };

    // ---- pipeline buffers (compile-time indexed after full unroll) ----
    u32x4 cb[2][4];     // corners  {00,01,10,11}
    u32x4 wb[2][4];     // weights  {mt0..mt3}

    auto issue = [&](int kt, int ks, int pb) {
        const int sl = kt & 1;
        const int ch = ks * 4 + kq;
        // weights first (longest latency, L2)
        const u32x4* wp = wsrc + (kt * 8 + ks * 4 + kq) * 64 + l15;
        wb[pb][0] = wp[0];  wb[pb][1] = wp[16];
        wb[pb][2] = wp[32]; wb[pb][3] = wp[48];
        // corners from LDS window
        cb[pb][0] = win[r0a[sl] + bx0a[sl] + (ch ^ sx0a[sl])];
        cb[pb][1] = win[r0a[sl] + bx1a[sl] + (ch ^ sx1a[sl])];
        cb[pb][2] = win[r1a[sl] + bx0a[sl] + (ch ^ sx0a[sl])];
        cb[pb][3] = win[r1a[sl] + bx1a[sl] + (ch ^ sx1a[sl])];
    };

    auto consume = [&](int kt, int ks, int pb) {
        const int sl = kt & 1;
        const int ch = ks * 4 + kq;
        u32x4 w00 = cb[pb][0], w01 = cb[pb][1];
        u32x4 w10 = cb[pb][2], w11 = cb[pb][3];
        if (!in0a[sl]) {                  // rare: |oy| past window
            w00 = *(const u32x4*)(nb + ((size_t)gy0a[sl] * WW + gx0a[sl]) * CC + ch * 8);
            w01 = *(const u32x4*)(nb + ((size_t)gy0a[sl] * WW + gx1a[sl]) * CC + ch * 8);
        }
        if (!in1a[sl]) {
            w10 = *(const u32x4*)(nb + ((size_t)gy1a[sl] * WW + gx0a[sl]) * CC + ch * 8);
            w11 = *(const u32x4*)(nb + ((size_t)gy1a[sl] * WW + gx1a[sl]) * CC + ch * 8);
        }
        const float c00 = c00a[sl], c01 = c01a[sl];
        const float c10 = c10a[sl], c11 = c11a[sl];
        u32x4 pk;
        #pragma unroll
        for (int j = 0; j < 4; ++j) {
            const float a0 = __uint_as_float(w00[j] << 16);
            const float a1 = __uint_as_float(w00[j] & 0xFFFF0000u);
            const float b0 = __uint_as_float(w01[j] << 16);
            const float b1 = __uint_as_float(w01[j] & 0xFFFF0000u);
            const float d0 = __uint_as_float(w10[j] << 16);
            const float d1 = __uint_as_float(w10[j] & 0xFFFF0000u);
            const float e0 = __uint_as_float(w11[j] << 16);
            const float e1 = __uint_as_float(w11[j] & 0xFFFF0000u);
            const float s0f = c00 * a0 + c01 * b0 + c10 * d0 + c11 * e0;
            const float s1f = c00 * a1 + c01 * b1 + c10 * d1 + c11 * e1;
            pk[j] = f32_to_bf16_rne(s0f) | (f32_to_bf16_rne(s1f) << 16);
        }
        const bf16x8 bfrag = __builtin_bit_cast(bf16x8, pk);
        #pragma unroll
        for (int mt = 0; mt < 4; ++mt) {
            const bf16x8 afrag = __builtin_bit_cast(bf16x8, wb[pb][mt]);
            acc[mt] = __builtin_amdgcn_mfma_f32_16x16x32_bf16(afrag, bfrag, acc[mt], 0, 0, 0);
        }
    };

    // ---- software-pipelined 18-stage loop (tap = s>>1, ks = s&1) ----
    stencil(0, 0);
    issue(0, 0, 0);
    #pragma unroll
    for (int s = 0; s < 18; ++s) {
        const int kt = s >> 1, ks = s & 1, pb = s & 1;
        if (s + 1 < 18) {
            const int nkt = (s + 1) >> 1, nks = (s + 1) & 1, npb = (s + 1) & 1;
            if (nks == 0) stencil(nkt, nkt & 1);
            issue(nkt, nks, npb);
        }
        consume(kt, ks, pb);
    }

    // ---- epilogue: C/D layout col=lane&15 (pixel), row=kq*4+reg (o) ----
    #pragma unroll
    for (int mt = 0; mt < 4; ++mt) {
        const f32x4 bv = *(const f32x4*)(bias + mt * 16 + kq * 4);
        #pragma unroll
        for (int r = 0; r < 4; ++r) {
            const int o = mt * 16 + kq * 4 + r;
            out[((b * 64 + o) * 128 + h) * 128 + wpix] = acc[mt][r] + bv[r];
        }
    }
}

extern "C" void kernel_launch(void* const* d_in, const int* in_sizes, int n_in,
                              void* d_out, int out_size, void* d_ws, size_t ws_size,
                              hipStream_t stream)
{
    const float* input  = (const float*)d_in[0];
    // d_in[1] = depth, unused by the reference
    const float* offset = (const float*)d_in[2];
    const float* mask   = (const float*)d_in[3];
    const float* weight = (const float*)d_in[4];
    const float* bias   = (const float*)d_in[5];
    float* out = (float*)d_out;

    unsigned short* nhwc = (unsigned short*)d_ws;                    // 8.39 MB
    unsigned short* wT2  = nhwc + (size_t)4 * HW * CC;               // 73728 B

    prep_fused13<<<dim3(2066), dim3(256), 0, stream>>>(input, nhwc, weight, wT2);
    ddc_pipe13<<<dim3(512), dim3(512), 0, stream>>>(nhwc, wT2, offset, mask, bias, out);
}